// Round 13
// baseline (145.961 us; speedup 1.0000x reference)
//
#include <hip/hip_runtime.h>
#include <hip/hip_fp16.h>
#include <stdint.h>

#define NN 100000
#define NE 1600000
#define DD 128

#define NBKT 391            // buckets of 256 rows: 391*256 = 100096 >= NN
#define CAPB 4480           // per-bucket record capacity (mean 4096, sd ~64, +6sd)
#define NBIN 3125           // 32-row bins: 3125*32 == NN exactly
#define GCAP 1024           // per-bin staged col capacity (mean 512, max ~650)

typedef _Float16 f16x8 __attribute__((ext_vector_type(8)));
typedef float f32x4 __attribute__((ext_vector_type(4)));

__device__ __forceinline__ uint32_t hadd2u(uint32_t a, uint32_t b){
  union { uint32_t u; __half2 h; } x, y;
  x.u = a; y.u = b;
  x.h = __hadd2(x.h, y.h);
  return x.u;
}
__device__ __forceinline__ uint32_t hmul2u(uint32_t a, __half2 m){
  union { uint32_t u; __half2 h; } x; x.u = a;
  x.h = __hmul2(x.h, m);
  return x.u;
}

// ---- pass 1: blocks 0-390 partition edges into fat buckets; 391-454 convert W ----
__global__ __launch_bounds__(256) void k_part1(
    const int* __restrict__ ei, int* __restrict__ bktres, uint32_t* __restrict__ ibuf,
    const float* __restrict__ w, uint16_t* __restrict__ wsw){
  int b = blockIdx.x, t = threadIdx.x;
  if (b < NBKT){                                     // ---- part1 ----
    __shared__ int sh[NBKT];
    int e0 = b*4096;
    for (int i=t; i<NBKT; i+=256) sh[i] = 0;
    __syncthreads();
    int rr[16], cc[16];
    #pragma unroll
    for (int j=0;j<16;j++){
      int e = e0 + j*256 + t;
      rr[j] = -1;
      if (e < NE){
        rr[j] = ei[e]; cc[j] = ei[NE + e];           // no self loops by construction
        atomicAdd(&sh[rr[j] >> 8], 1);
      }
    }
    __syncthreads();
    for (int i=t; i<NBKT; i+=256){
      int v = sh[i];
      sh[i] = v ? atomicAdd(&bktres[i*16], v) : 0;   // reserve contiguous chunk
    }
    __syncthreads();
    #pragma unroll
    for (int j=0;j<16;j++){
      if (rr[j] >= 0){
        int bk = rr[j] >> 8;
        int p = atomicAdd(&sh[bk], 1);
        if (p < CAPB)
          ibuf[(size_t)bk*CAPB + p] = (uint32_t)(((rr[j] & 255) << 17) | cc[j]);
      }
    }
  } else {                                           // ---- W -> frag-linear f16 ----
    int wi = (b - NBKT)*256 + t;                     // 64 blocks, < 16384 exact
    int j = wi & 7, l = (wi >> 3) & 63, kt = (wi >> 9) & 3, ct = wi >> 11;
    int k = kt*32 + ((l >> 4) & 3)*8 + j;
    int d = ct*16 + (l & 15);
    union { _Float16 h; uint16_t u; } cv; cv.h = (_Float16)w[k*DD + d];
    wsw[wi] = cv.u;
  }
}

// ---- mid: blocks 0-390 sort each bucket by row in LDS; blocks 391-12890 stream
//      x -> f16 SLICE-MAJOR xs[slice][node][8 words] (16 dims per slice) ----
__global__ __launch_bounds__(256) void k_mid(
    const int* __restrict__ bktres, uint32_t* __restrict__ ibuf,
    uint32_t* __restrict__ rowinfo,
    const float4* __restrict__ x, uint32_t* __restrict__ xs){
  int t = threadIdx.x, b = blockIdx.x;
  if (b >= NBKT){                                    // ---- x -> f16 slice-major ----
    int i = (b - NBKT)*256 + t;                      // 12500 blocks = 3.2M exact
    float4 v = x[i];
    union { _Float16 h[4]; uint2 u; } r;
    r.h[0] = (_Float16)v.x; r.h[1] = (_Float16)v.y;
    r.h[2] = (_Float16)v.z; r.h[3] = (_Float16)v.w;
    int n = i >> 5, dq = i & 31;                     // node, 4-dim quad 0..31
    uint32_t* dst = xs + (size_t)(dq >> 2)*NN*8 + (size_t)n*8 + (dq & 3)*2;
    *(uint2*)dst = r.u;                              // 64B-line-clean per slice per wave
    return;
  }
  // ---- part2: bucket sort ----
  __shared__ uint32_t s_rec[CAPB];                   // 17.9 KB
  __shared__ int s_deg[256], s_off[256], s_cur[256];
  int lane = t & 63, wid = t >> 6;
  int cnt = bktres[b*16]; if (cnt > CAPB) cnt = CAPB;
  size_t bb = (size_t)b*CAPB;
  s_deg[t] = 0;
  __syncthreads();
  for (int i=t; i<cnt; i+=256){
    uint32_t rec = ibuf[bb + i];
    s_rec[i] = rec;
    atomicAdd(&s_deg[rec >> 17], 1);
  }
  __syncthreads();
  if (wid == 0){                                     // wave-0 scan of 256 degs
    int carry = 0;
    for (int ch=0; ch<4; ch++){
      int idx = ch*64 + lane;
      int o = s_deg[idx], v = o;
      #pragma unroll
      for (int d=1; d<64; d<<=1){ int y = __shfl_up(v, d); if (lane >= d) v += y; }
      int ex = carry + v - o;
      s_off[idx] = ex; s_cur[idx] = ex;
      carry += __shfl(v, 63);
    }
  }
  __syncthreads();
  int dgc = s_deg[t] > 255 ? 255 : s_deg[t];
  rowinfo[b*256 + t] = ((uint32_t)s_off[t] << 8) | (uint32_t)dgc;
  for (int i=t; i<cnt; i+=256){
    uint32_t rec = s_rec[i];
    int p = atomicAdd(&s_cur[rec >> 17], 1);
    ibuf[bb + p] = rec & 0x1FFFFu;                   // col only, row-sorted, L2-hot
  }
}

// ---- gather, XCD-local: block b -> (bin b>>3, slice b&7). Each wave: 8 rows x 8
//      words; one wave-load covers 8 edges' 32B slice rows; lane-local accum. ----
__global__ __launch_bounds__(256) void k_gather(
    const uint32_t* __restrict__ xs, const uint32_t* __restrict__ ibuf,
    const uint32_t* __restrict__ rowinfo, uint32_t* __restrict__ aggS){
  __shared__ int s_col[GCAP];                        // 4 KB
  __shared__ int s_loc[32], s_deg[32];
  int t = threadIdx.x, wid = t >> 6, lane = t & 63;
  int b = blockIdx.x;
  int bin = b >> 3, slice = b & 7;                   // blockIdx%8 -> XCD (round-robin)
  int row0 = bin << 5;
  if (t < 32){
    uint32_t info = rowinfo[row0 + t];
    s_loc[t] = (int)(info >> 8);
    s_deg[t] = (int)(info & 255u);
  }
  __syncthreads();
  int base = s_loc[0];
  int len = s_loc[31] + s_deg[31] - base; if (len > GCAP) len = GCAP;
  size_t bb = (size_t)(row0 >> 8)*CAPB + base;
  for (int i=t; i<len; i+=256) s_col[i] = (int)ibuf[bb + i];
  __syncthreads();

  int j = lane >> 3, w = lane & 7;                   // row sub-index, word-in-slice
  int lr = wid*8 + j;
  int r = row0 + lr;
  int dg = s_deg[lr], off = s_loc[lr] - base;
  const uint32_t* xsl = xs + (size_t)slice*NN*8;     // 3.2 MB, L2-resident on this XCD
  uint32_t acc = 0u;
  int md = dg;
  md = max(md, __shfl_xor(md, 8));
  md = max(md, __shfl_xor(md, 16));
  md = max(md, __shfl_xor(md, 32));                  // max deg over the wave's 8 rows
  int s = 0;
  for (; s+4 <= md; s += 4){                         // 4 wave-loads = 32 edges in flight
    int i0 = off + ((s+0 < dg) ? s+0 : 0);
    int i1 = off + ((s+1 < dg) ? s+1 : 0);
    int i2 = off + ((s+2 < dg) ? s+2 : 0);
    int i3 = off + ((s+3 < dg) ? s+3 : 0);
    int c0 = s_col[i0], c1 = s_col[i1], c2 = s_col[i2], c3 = s_col[i3];
    uint32_t v0 = xsl[(size_t)c0*8 + w];
    uint32_t v1 = xsl[(size_t)c1*8 + w];
    uint32_t v2 = xsl[(size_t)c2*8 + w];
    uint32_t v3 = xsl[(size_t)c3*8 + w];
    if (s+0 < dg) acc = hadd2u(acc, v0);
    if (s+1 < dg) acc = hadd2u(acc, v1);
    if (s+2 < dg) acc = hadd2u(acc, v2);
    if (s+3 < dg) acc = hadd2u(acc, v3);
  }
  for (; s < md; s++){
    int i0 = off + ((s < dg) ? s : 0);
    uint32_t v0 = xsl[(size_t)s_col[i0]*8 + w];
    if (s < dg) acc = hadd2u(acc, v0);
  }
  acc = hadd2u(acc, xsl[(size_t)r*8 + w]);           // self
  acc = hmul2u(acc, __float2half2_rn(1.0f / (float)(dg + 1)));
  aggS[(size_t)slice*NN*8 + (size_t)r*8 + w] = acc;  // 256B contiguous per wave
}

// ---- LDS-free 16-row-per-wave GEMM (f16 MFMA) + row L2-normalize;
//      A-frags read from slice-major agg ----
__global__ __launch_bounds__(256) void k_gemm(const uint16_t* __restrict__ agg,
                                              const uint16_t* __restrict__ wsw,
                                              float* __restrict__ out){
  int tid = threadIdx.x, wid = tid >> 6, lane = tid & 63;
  int g = blockIdx.x*4 + wid;                        // 16-row group
  if (g >= 6250) return;                             // wave-uniform pad exit (6250*16 == NN)
  const char* aggb = (const char*)agg;
  const f16x8* Bf = (const f16x8*)wsw;
  int row = g*16 + (lane & 15), gk = lane >> 4;
  f16x8 a[4];
  #pragma unroll
  for (int kt=0; kt<4; kt++){
    int d0 = kt*32 + gk*8;                           // starting dim of this frag
    int slice = d0 >> 4;
    a[kt] = *(const f16x8*)(aggb + (size_t)slice*NN*32 + (size_t)row*32 + ((d0 >> 3) & 1)*16);
  }

  f32x4 acc[8];
  #pragma unroll
  for (int ct=0;ct<8;ct++) acc[ct] = (f32x4){0.f,0.f,0.f,0.f};
  #pragma unroll
  for (int ct=0;ct<8;ct++){
    #pragma unroll
    for (int kt=0;kt<4;kt++)
      acc[ct] = __builtin_amdgcn_mfma_f32_16x16x32_f16(a[kt], Bf[(ct*4+kt)*64 + lane], acc[ct], 0, 0, 0);
  }
  float sq[4] = {0.f,0.f,0.f,0.f};
  #pragma unroll
  for (int ct=0;ct<8;ct++){
    #pragma unroll
    for (int i=0;i<4;i++) sq[i] += acc[ct][i]*acc[ct][i];
  }
  #pragma unroll
  for (int m=1;m<16;m<<=1){
    #pragma unroll
    for (int i=0;i<4;i++) sq[i] += __shfl_xor(sq[i], m);
  }
  float sc4[4];
  #pragma unroll
  for (int i=0;i<4;i++) sc4[i] = 1.0f / fmaxf(sqrtf(sq[i]), 1e-12f);

  int col = lane & 15;
  int rb = g*16 + (gk << 2);
  #pragma unroll
  for (int i=0;i<4;i++){
    int n = rb + i;                                  // always < NN (no partial tiles)
    #pragma unroll
    for (int ct=0;ct<8;ct++)
      out[(size_t)n*DD + (ct<<4) + col] = acc[ct][i]*sc4[i];
  }
}

extern "C" void kernel_launch(void* const* d_in, const int* in_sizes, int n_in,
                              void* d_out, int out_size, void* d_ws, size_t ws_size,
                              hipStream_t stream){
  const float* x = (const float*)d_in[0];
  const int*  ei = (const int*)d_in[1];
  const float* w = (const float*)d_in[2];
  float* out = (float*)d_out;
  char* ws = (char*)d_ws;
  (void)in_sizes; (void)n_in; (void)out_size; (void)ws_size;

  size_t off = 0;
  uint32_t* xs  = (uint32_t*)(ws + off); off += (size_t)NN*DD*2;         // 25,600,000 (slice-major)
  uint16_t* agg = (uint16_t*)(ws + off); off += (size_t)NN*DD*2;         // 25,600,000 (slice-major)
  uint16_t* wsw = (uint16_t*)(ws + off); off += (size_t)DD*DD*2;         // 32,768
  uint32_t* ibuf = (uint32_t*)(ws + off); off += (size_t)NBKT*CAPB*4;    // 7,006,720
  int* bktres   = (int*)(ws + off); off += (size_t)NBKT*16*4;            // 25,024
  uint32_t* rowinfo = (uint32_t*)(ws + off); off += (size_t)NBKT*256*4;  // 400,384 (~58.7 MB)

  hipMemsetAsync(bktres, 0, (size_t)NBKT*16*4, stream);
  k_part1<<<NBKT + 64, 256, 0, stream>>>(ei, bktres, ibuf, w, wsw);
  k_mid<<<NBKT + 12500, 256, 0, stream>>>(bktres, ibuf, rowinfo, (const float4*)x, xs);
  k_gather<<<NBIN*8, 256, 0, stream>>>(xs, ibuf, rowinfo, (uint32_t*)agg);
  k_gemm<<<1563, 256, 0, stream>>>(agg, wsw, out);
}

// Round 14
// 139.432 us; speedup vs baseline: 1.0468x; 1.0468x over previous
//
#include <hip/hip_runtime.h>
#include <hip/hip_fp16.h>
#include <stdint.h>

#define NN 100000
#define NNP 100008          // per-slice row stride (row NN = zero sentinel)
#define NE 1600000
#define DD 128

#define NBKT 391            // buckets of 256 rows: 391*256 = 100096 >= NN
#define CAPB 4480           // per-bucket record capacity (mean 4096, sd ~64, +6sd)
#define NQ 782              // 128-row quads: 782*128 = 100096 >= NN
#define QCAP 2944           // s_col array (allows md-overrun reads)
#define QLEN 2688           // staged cols cap per quad (mean 2048, +11sd)

typedef _Float16 f16x8 __attribute__((ext_vector_type(8)));
typedef float f32x4 __attribute__((ext_vector_type(4)));

__device__ __forceinline__ uint32_t hadd2u(uint32_t a, uint32_t b){
  union { uint32_t u; __half2 h; } x, y;
  x.u = a; y.u = b;
  x.h = __hadd2(x.h, y.h);
  return x.u;
}
__device__ __forceinline__ uint32_t hmul2u(uint32_t a, __half2 m){
  union { uint32_t u; __half2 h; } x; x.u = a;
  x.h = __hmul2(x.h, m);
  return x.u;
}

// ---- pass 1: blocks 0-390 partition edges into fat buckets; 391-454 convert W;
//      block 455 zeroes the per-slice sentinel rows ----
__global__ __launch_bounds__(256) void k_part1(
    const int* __restrict__ ei, int* __restrict__ bktres, uint32_t* __restrict__ ibuf,
    const float* __restrict__ w, uint16_t* __restrict__ wsw, uint32_t* __restrict__ xs){
  int b = blockIdx.x, t = threadIdx.x;
  if (b < NBKT){                                     // ---- part1 ----
    __shared__ int sh[NBKT];
    int e0 = b*4096;
    for (int i=t; i<NBKT; i+=256) sh[i] = 0;
    __syncthreads();
    int rr[16], cc[16];
    #pragma unroll
    for (int j=0;j<16;j++){
      int e = e0 + j*256 + t;
      rr[j] = -1;
      if (e < NE){
        rr[j] = ei[e]; cc[j] = ei[NE + e];           // no self loops by construction
        atomicAdd(&sh[rr[j] >> 8], 1);
      }
    }
    __syncthreads();
    for (int i=t; i<NBKT; i+=256){
      int v = sh[i];
      sh[i] = v ? atomicAdd(&bktres[i*16], v) : 0;   // reserve contiguous chunk
    }
    __syncthreads();
    #pragma unroll
    for (int j=0;j<16;j++){
      if (rr[j] >= 0){
        int bk = rr[j] >> 8;
        int p = atomicAdd(&sh[bk], 1);
        if (p < CAPB)
          ibuf[(size_t)bk*CAPB + p] = (uint32_t)(((rr[j] & 255) << 17) | cc[j]);
      }
    }
  } else if (b < NBKT + 64){                         // ---- W -> frag-linear f16 ----
    int wi = (b - NBKT)*256 + t;                     // 64 blocks, 16384 exact
    int j = wi & 7, l = (wi >> 3) & 63, kt = (wi >> 9) & 3, ct = wi >> 11;
    int k = kt*32 + ((l >> 4) & 3)*8 + j;
    int d = ct*16 + (l & 15);
    union { _Float16 h; uint16_t u; } cv; cv.h = (_Float16)w[k*DD + d];
    wsw[wi] = cv.u;
  } else {                                           // ---- zero sentinel rows ----
    if (t < 64) xs[(size_t)(t >> 3)*NNP*8 + (size_t)NN*8 + (t & 7)] = 0u;
  }
}

// ---- mid: blocks 0-390 sort each bucket by row in LDS; blocks 391-12890 stream
//      x -> f16 SLICE-MAJOR xs[slice][node<NNP][8 words] (16 dims per slice) ----
__global__ __launch_bounds__(256) void k_mid(
    const int* __restrict__ bktres, uint32_t* __restrict__ ibuf,
    uint32_t* __restrict__ rowinfo,
    const float4* __restrict__ x, uint32_t* __restrict__ xs){
  int t = threadIdx.x, b = blockIdx.x;
  if (b >= NBKT){                                    // ---- x -> f16 slice-major ----
    int i = (b - NBKT)*256 + t;                      // 12500 blocks = 3.2M exact
    float4 v = x[i];
    union { _Float16 h[4]; uint2 u; } r;
    r.h[0] = (_Float16)v.x; r.h[1] = (_Float16)v.y;
    r.h[2] = (_Float16)v.z; r.h[3] = (_Float16)v.w;
    int n = i >> 5, dq = i & 31;                     // node, 4-dim quad 0..31
    uint32_t* dst = xs + (size_t)(dq >> 2)*NNP*8 + (size_t)n*8 + (dq & 3)*2;
    *(uint2*)dst = r.u;
    return;
  }
  // ---- part2: bucket sort ----
  __shared__ uint32_t s_rec[CAPB];                   // 17.9 KB
  __shared__ int s_deg[256], s_off[256], s_cur[256];
  int lane = t & 63, wid = t >> 6;
  int cnt = bktres[b*16]; if (cnt > CAPB) cnt = CAPB;
  size_t bb = (size_t)b*CAPB;
  s_deg[t] = 0;
  __syncthreads();
  for (int i=t; i<cnt; i+=256){
    uint32_t rec = ibuf[bb + i];
    s_rec[i] = rec;
    atomicAdd(&s_deg[rec >> 17], 1);
  }
  __syncthreads();
  if (wid == 0){                                     // wave-0 scan of 256 degs
    int carry = 0;
    for (int ch=0; ch<4; ch++){
      int idx = ch*64 + lane;
      int o = s_deg[idx], v = o;
      #pragma unroll
      for (int d=1; d<64; d<<=1){ int y = __shfl_up(v, d); if (lane >= d) v += y; }
      int ex = carry + v - o;
      s_off[idx] = ex; s_cur[idx] = ex;
      carry += __shfl(v, 63);
    }
  }
  __syncthreads();
  int dgc = s_deg[t] > 255 ? 255 : s_deg[t];
  rowinfo[b*256 + t] = ((uint32_t)s_off[t] << 8) | (uint32_t)dgc;
  for (int i=t; i<cnt; i+=256){
    uint32_t rec = s_rec[i];
    int p = atomicAdd(&s_cur[rec >> 17], 1);
    ibuf[bb + p] = rec & 0x1FFFFu;                   // col only, row-sorted, L2-hot
  }
}

// ---- gather, XCD-local + wide: block b -> (quad b>>3, slice b&7); wave = one
//      32-row bin; lane = (row lane>>1, uint4-half lane&1); 1 wave-load = 32 edges ----
__global__ __launch_bounds__(256) void k_gather(
    const uint4* __restrict__ xs4, const uint32_t* __restrict__ ibuf,
    const uint32_t* __restrict__ rowinfo, uint4* __restrict__ agg4){
  __shared__ int s_col[QCAP];                        // 11.8 KB
  int t = threadIdx.x, wid = t >> 6, lane = t & 63;
  int b = blockIdx.x;
  int q = b >> 3, slice = b & 7;                     // blockIdx%8 -> XCD (round-robin)
  int qrow0 = q << 7;                                // 128-row quad (bucket-aligned)
  int lastrow = qrow0 + 127; if (lastrow >= NN) lastrow = NN - 1;
  uint32_t binfo = rowinfo[qrow0];
  uint32_t linfo = rowinfo[lastrow];
  int base = (int)(binfo >> 8);
  int len = (int)(linfo >> 8) + (int)(linfo & 255u) - base;
  if (len > QLEN) len = QLEN;
  size_t bb = (size_t)(qrow0 >> 8)*CAPB + base;
  for (int i=t; i<len; i+=256) s_col[i] = (int)ibuf[bb + i];
  __syncthreads();

  int r = qrow0 + wid*32 + (lane >> 1);              // wave-uniform validity
  if (r >= NN) return;                               // only pad waves of last quad
  int w4 = lane & 1;
  uint32_t info = rowinfo[r];
  int off = (int)(info >> 8) - base;
  int dg = (int)(info & 255u);
  const uint4* xsl = xs4 + (size_t)slice*NNP*2;      // 3.2 MB slice, L2-resident
  uint32_t a0 = 0u, a1 = 0u, a2 = 0u, a3 = 0u;
  int md = dg;
  md = max(md, __shfl_xor(md, 2));
  md = max(md, __shfl_xor(md, 4));
  md = max(md, __shfl_xor(md, 8));
  md = max(md, __shfl_xor(md, 16));
  md = max(md, __shfl_xor(md, 32));                  // max deg over the wave's 32 rows
  for (int s = 0; s < md; s += 4){                   // 4 x 1KB wave-loads in flight
    int c0 = (s+0 < dg) ? s_col[off+s+0] : NN;       // NN = zero sentinel row
    int c1 = (s+1 < dg) ? s_col[off+s+1] : NN;
    int c2 = (s+2 < dg) ? s_col[off+s+2] : NN;
    int c3 = (s+3 < dg) ? s_col[off+s+3] : NN;
    uint4 v0 = xsl[(size_t)c0*2 + w4];
    uint4 v1 = xsl[(size_t)c1*2 + w4];
    uint4 v2 = xsl[(size_t)c2*2 + w4];
    uint4 v3 = xsl[(size_t)c3*2 + w4];
    a0 = hadd2u(a0, v0.x); a1 = hadd2u(a1, v0.y); a2 = hadd2u(a2, v0.z); a3 = hadd2u(a3, v0.w);
    a0 = hadd2u(a0, v1.x); a1 = hadd2u(a1, v1.y); a2 = hadd2u(a2, v1.z); a3 = hadd2u(a3, v1.w);
    a0 = hadd2u(a0, v2.x); a1 = hadd2u(a1, v2.y); a2 = hadd2u(a2, v2.z); a3 = hadd2u(a3, v2.w);
    a0 = hadd2u(a0, v3.x); a1 = hadd2u(a1, v3.y); a2 = hadd2u(a2, v3.z); a3 = hadd2u(a3, v3.w);
  }
  uint4 sv = xsl[(size_t)r*2 + w4];                  // self
  a0 = hadd2u(a0, sv.x); a1 = hadd2u(a1, sv.y); a2 = hadd2u(a2, sv.z); a3 = hadd2u(a3, sv.w);
  __half2 inv2 = __float2half2_rn(1.0f / (float)(dg + 1));
  uint4 res;
  res.x = hmul2u(a0, inv2); res.y = hmul2u(a1, inv2);
  res.z = hmul2u(a2, inv2); res.w = hmul2u(a3, inv2);
  agg4[(size_t)slice*NN*2 + (size_t)r*2 + w4] = res; // 1KB contiguous per wave
}

// ---- LDS-free 16-row-per-wave GEMM (f16 MFMA) + row L2-normalize;
//      A-frags read from slice-major agg ----
__global__ __launch_bounds__(256) void k_gemm(const uint16_t* __restrict__ agg,
                                              const uint16_t* __restrict__ wsw,
                                              float* __restrict__ out){
  int tid = threadIdx.x, wid = tid >> 6, lane = tid & 63;
  int g = blockIdx.x*4 + wid;                        // 16-row group
  if (g >= 6250) return;                             // wave-uniform pad exit (6250*16 == NN)
  const char* aggb = (const char*)agg;
  const f16x8* Bf = (const f16x8*)wsw;
  int row = g*16 + (lane & 15), gk = lane >> 4;
  f16x8 a[4];
  #pragma unroll
  for (int kt=0; kt<4; kt++){
    int d0 = kt*32 + gk*8;                           // starting dim of this frag
    int slice = d0 >> 4;
    a[kt] = *(const f16x8*)(aggb + (size_t)slice*NN*32 + (size_t)row*32 + ((d0 >> 3) & 1)*16);
  }

  f32x4 acc[8];
  #pragma unroll
  for (int ct=0;ct<8;ct++) acc[ct] = (f32x4){0.f,0.f,0.f,0.f};
  #pragma unroll
  for (int ct=0;ct<8;ct++){
    #pragma unroll
    for (int kt=0;kt<4;kt++)
      acc[ct] = __builtin_amdgcn_mfma_f32_16x16x32_f16(a[kt], Bf[(ct*4+kt)*64 + lane], acc[ct], 0, 0, 0);
  }
  float sq[4] = {0.f,0.f,0.f,0.f};
  #pragma unroll
  for (int ct=0;ct<8;ct++){
    #pragma unroll
    for (int i=0;i<4;i++) sq[i] += acc[ct][i]*acc[ct][i];
  }
  #pragma unroll
  for (int m=1;m<16;m<<=1){
    #pragma unroll
    for (int i=0;i<4;i++) sq[i] += __shfl_xor(sq[i], m);
  }
  float sc4[4];
  #pragma unroll
  for (int i=0;i<4;i++) sc4[i] = 1.0f / fmaxf(sqrtf(sq[i]), 1e-12f);

  int col = lane & 15;
  int rb = g*16 + (gk << 2);
  #pragma unroll
  for (int i=0;i<4;i++){
    int n = rb + i;                                  // always < NN (no partial tiles)
    #pragma unroll
    for (int ct=0;ct<8;ct++)
      out[(size_t)n*DD + (ct<<4) + col] = acc[ct][i]*sc4[i];
  }
}

extern "C" void kernel_launch(void* const* d_in, const int* in_sizes, int n_in,
                              void* d_out, int out_size, void* d_ws, size_t ws_size,
                              hipStream_t stream){
  const float* x = (const float*)d_in[0];
  const int*  ei = (const int*)d_in[1];
  const float* w = (const float*)d_in[2];
  float* out = (float*)d_out;
  char* ws = (char*)d_ws;
  (void)in_sizes; (void)n_in; (void)out_size; (void)ws_size;

  size_t off = 0;
  uint32_t* xs  = (uint32_t*)(ws + off); off += (size_t)NNP*8*32;       // 25,602,048 (slice-major + sentinel)
  uint16_t* agg = (uint16_t*)(ws + off); off += (size_t)NN*DD*2;        // 25,600,000 (slice-major)
  uint16_t* wsw = (uint16_t*)(ws + off); off += (size_t)DD*DD*2;        // 32,768
  uint32_t* ibuf = (uint32_t*)(ws + off); off += (size_t)NBKT*CAPB*4;   // 7,006,720
  int* bktres   = (int*)(ws + off); off += (size_t)NBKT*16*4;           // 25,024
  uint32_t* rowinfo = (uint32_t*)(ws + off); off += (size_t)NBKT*256*4; // 400,384 (~58.7 MB)

  hipMemsetAsync(bktres, 0, (size_t)NBKT*16*4, stream);
  k_part1<<<NBKT + 65, 256, 0, stream>>>(ei, bktres, ibuf, w, wsw, xs);
  k_mid<<<NBKT + 12500, 256, 0, stream>>>(bktres, ibuf, rowinfo, (const float4*)x, xs);
  k_gather<<<NQ*8, 256, 0, stream>>>((const uint4*)xs, ibuf, rowinfo, (uint4*)agg);
  k_gemm<<<1563, 256, 0, stream>>>(agg, wsw, out);
}

// Round 15
// 127.933 us; speedup vs baseline: 1.1409x; 1.0899x over previous
//
#include <hip/hip_runtime.h>
#include <hip/hip_fp16.h>
#include <stdint.h>

#define NN 100000
#define NE 1600000
#define DD 128

#define NBKT 391            // buckets of 256 rows: 391*256 = 100096 >= NN
#define CAPB 4480           // per-bucket record capacity (mean 4096, sd ~64, +6sd)
#define NBIN 3125           // 32-row bins: 3125*32 == NN exactly
#define GCAP 1024           // per-bin staged col capacity (mean 512, max ~650)

typedef _Float16 f16x8 __attribute__((ext_vector_type(8)));
typedef float f32x4 __attribute__((ext_vector_type(4)));

__device__ __forceinline__ uint32_t hadd2u(uint32_t a, uint32_t b){
  union { uint32_t u; __half2 h; } x, y;
  x.u = a; y.u = b;
  x.h = __hadd2(x.h, y.h);
  return x.u;
}
__device__ __forceinline__ uint32_t hmul2u(uint32_t a, __half2 m){
  union { uint32_t u; __half2 h; } x; x.u = a;
  x.h = __hmul2(x.h, m);
  return x.u;
}

// ---- front (512-thr): blocks 0-390 partition edges into fat buckets (8-iter
//      chains); 391-6640 convert x -> f16; 6641-6672 convert W (backfill) ----
__global__ __launch_bounds__(512) void k_front(
    const int* __restrict__ ei, int* __restrict__ bktres, uint32_t* __restrict__ ibuf,
    const float4* __restrict__ x, uint2* __restrict__ x16,
    const float* __restrict__ w, uint16_t* __restrict__ wsw){
  int b = blockIdx.x, t = threadIdx.x;
  if (b < NBKT){                                     // ---- part1 ----
    __shared__ int sh[NBKT];
    int e0 = b*4096;
    for (int i=t; i<NBKT; i+=512) sh[i] = 0;
    __syncthreads();
    int rr[8], cc[8];
    #pragma unroll
    for (int j=0;j<8;j++){
      int e = e0 + j*512 + t;
      rr[j] = -1;
      if (e < NE){
        rr[j] = ei[e]; cc[j] = ei[NE + e];           // no self loops by construction
        atomicAdd(&sh[rr[j] >> 8], 1);
      }
    }
    __syncthreads();
    for (int i=t; i<NBKT; i+=512){
      int v = sh[i];
      sh[i] = v ? atomicAdd(&bktres[i*16], v) : 0;   // reserve contiguous chunk
    }
    __syncthreads();
    #pragma unroll
    for (int j=0;j<8;j++){
      if (rr[j] >= 0){
        int bk = rr[j] >> 8;
        int p = atomicAdd(&sh[bk], 1);
        if (p < CAPB)
          ibuf[(size_t)bk*CAPB + p] = (uint32_t)(((rr[j] & 255) << 17) | cc[j]);
      }
    }
  } else if (b < 6641){                              // ---- x -> f16 ----
    int i = (b - NBKT)*512 + t;                      // 6250 blocks = 3.2M float4 exact
    float4 v = x[i];
    union { _Float16 h[4]; uint2 u; } r;
    r.h[0] = (_Float16)v.x; r.h[1] = (_Float16)v.y;
    r.h[2] = (_Float16)v.z; r.h[3] = (_Float16)v.w;
    x16[i] = r.u;
  } else {                                           // ---- W -> frag-linear f16 ----
    int wi = (b - 6641)*512 + t;                     // 32 blocks = 16384 exact
    int j = wi & 7, l = (wi >> 3) & 63, kt = (wi >> 9) & 3, ct = wi >> 11;
    int k = kt*32 + ((l >> 4) & 3)*8 + j;
    int d = ct*16 + (l & 15);
    union { _Float16 h; uint16_t u; } cv; cv.h = (_Float16)w[k*DD + d];
    wsw[wi] = cv.u;
  }
}

// ---- pass 2 (512-thr): sort each bucket by row in LDS; cols back in-place + rowinfo ----
__global__ __launch_bounds__(512) void k_part2(const int* __restrict__ bktres,
                                               uint32_t* __restrict__ ibuf,
                                               uint32_t* __restrict__ rowinfo){
  __shared__ uint32_t s_rec[CAPB];                   // 17.9 KB
  __shared__ int s_deg[256], s_off[256], s_cur[256];
  int t = threadIdx.x, lane = t & 63, wid = t >> 6;
  int b = blockIdx.x;
  int cnt = bktres[b*16]; if (cnt > CAPB) cnt = CAPB;
  size_t bb = (size_t)b*CAPB;
  if (t < 256) s_deg[t] = 0;
  __syncthreads();
  for (int i=t; i<cnt; i+=512){
    uint32_t rec = ibuf[bb + i];
    s_rec[i] = rec;
    atomicAdd(&s_deg[rec >> 17], 1);
  }
  __syncthreads();
  if (wid == 0){                                     // wave-0 scan of 256 degs
    int carry = 0;
    for (int ch=0; ch<4; ch++){
      int idx = ch*64 + lane;
      int o = s_deg[idx], v = o;
      #pragma unroll
      for (int d=1; d<64; d<<=1){ int y = __shfl_up(v, d); if (lane >= d) v += y; }
      int ex = carry + v - o;
      s_off[idx] = ex; s_cur[idx] = ex;
      carry += __shfl(v, 63);
    }
  }
  __syncthreads();
  if (t < 256){
    int dgc = s_deg[t] > 255 ? 255 : s_deg[t];
    rowinfo[b*256 + t] = ((uint32_t)s_off[t] << 8) | (uint32_t)dgc;
  }
  for (int i=t; i<cnt; i+=512){
    uint32_t rec = s_rec[i];
    int p = atomicAdd(&s_cur[rec >> 17], 1);
    ibuf[bb + p] = rec & 0x1FFFFu;                   // col only, row-sorted, L2-hot
  }
}

// ---- gather: 32-row bin per 256-thr block, 4 waves x 8 rows; dual-edge f16 mean;
//      row-major coalesced agg store (256 B/row) ----
__global__ __launch_bounds__(256) void k_gather(
    const uint2* __restrict__ xp, const uint32_t* __restrict__ ibuf,
    const uint32_t* __restrict__ rowinfo, uint32_t* __restrict__ agg32){
  __shared__ int s_col[GCAP];                        // 4 KB
  __shared__ int s_loc[32], s_deg[32];
  int t = threadIdx.x, wid = t >> 6, lane = t & 63;
  int b = blockIdx.x;
  int row0 = b << 5;                                 // 32 rows, all inside bucket row0>>8
  if (t < 32){
    uint32_t info = rowinfo[row0 + t];
    s_loc[t] = (int)(info >> 8);
    s_deg[t] = (int)(info & 255u);
  }
  __syncthreads();
  int base = s_loc[0];
  int len = s_loc[31] + s_deg[31] - base; if (len > GCAP) len = GCAP;
  size_t bb = (size_t)(row0 >> 8)*CAPB + base;
  for (int i=t; i<len; i+=256) s_col[i] = (int)ibuf[bb + i];
  __syncthreads();

  int q = lane & 31, half = lane >> 5;               // lanes 0-31 even edges, 32-63 odd
  for (int lr = wid; lr < 32; lr += 4){
    int n = row0 + lr;
    int dg  = s_deg[lr];
    int off = s_loc[lr] - base;
    uint2 sv = xp[(size_t)n*32 + q];                 // self f16x4: dims 4q..4q+3
    uint32_t a01 = 0u, a23 = 0u;                     // packed f16x2 accumulators
    int j = 0;
    for (; j+16 <= dg; j += 16){                     // 8 dual loads in flight
      int c0 = s_col[off+j+half],    c1 = s_col[off+j+2+half];
      int c2 = s_col[off+j+4+half],  c3 = s_col[off+j+6+half];
      int c4 = s_col[off+j+8+half],  c5 = s_col[off+j+10+half];
      int c6 = s_col[off+j+12+half], c7 = s_col[off+j+14+half];
      uint2 v0 = xp[(size_t)c0*32 + q]; uint2 v1 = xp[(size_t)c1*32 + q];
      uint2 v2 = xp[(size_t)c2*32 + q]; uint2 v3 = xp[(size_t)c3*32 + q];
      uint2 v4 = xp[(size_t)c4*32 + q]; uint2 v5 = xp[(size_t)c5*32 + q];
      uint2 v6 = xp[(size_t)c6*32 + q]; uint2 v7 = xp[(size_t)c7*32 + q];
      a01 = hadd2u(a01, v0.x); a23 = hadd2u(a23, v0.y);
      a01 = hadd2u(a01, v1.x); a23 = hadd2u(a23, v1.y);
      a01 = hadd2u(a01, v2.x); a23 = hadd2u(a23, v2.y);
      a01 = hadd2u(a01, v3.x); a23 = hadd2u(a23, v3.y);
      a01 = hadd2u(a01, v4.x); a23 = hadd2u(a23, v4.y);
      a01 = hadd2u(a01, v5.x); a23 = hadd2u(a23, v5.y);
      a01 = hadd2u(a01, v6.x); a23 = hadd2u(a23, v6.y);
      a01 = hadd2u(a01, v7.x); a23 = hadd2u(a23, v7.y);
    }
    for (; j+8 <= dg; j += 8){
      int c0 = s_col[off+j+half],   c1 = s_col[off+j+2+half];
      int c2 = s_col[off+j+4+half], c3 = s_col[off+j+6+half];
      uint2 v0 = xp[(size_t)c0*32 + q]; uint2 v1 = xp[(size_t)c1*32 + q];
      uint2 v2 = xp[(size_t)c2*32 + q]; uint2 v3 = xp[(size_t)c3*32 + q];
      a01 = hadd2u(a01, v0.x); a23 = hadd2u(a23, v0.y);
      a01 = hadd2u(a01, v1.x); a23 = hadd2u(a23, v1.y);
      a01 = hadd2u(a01, v2.x); a23 = hadd2u(a23, v2.y);
      a01 = hadd2u(a01, v3.x); a23 = hadd2u(a23, v3.y);
    }
    for (; j+2 <= dg; j += 2){
      int c0 = s_col[off+j+half];
      uint2 v0 = xp[(size_t)c0*32 + q];
      a01 = hadd2u(a01, v0.x); a23 = hadd2u(a23, v0.y);
    }
    if (j < dg){                                     // odd tail: half 0 only
      int c0 = s_col[off+j];
      uint2 v0 = xp[(size_t)c0*32 + q];
      a01 = hadd2u(a01, half ? 0u : v0.x);
      a23 = hadd2u(a23, half ? 0u : v0.y);
    }
    a01 = hadd2u(a01, (uint32_t)__shfl_xor((int)a01, 32));
    a23 = hadd2u(a23, (uint32_t)__shfl_xor((int)a23, 32));
    __half2 inv2 = __float2half2_rn(1.0f / (float)(dg + 1));
    uint32_t r01 = hmul2u(hadd2u(a01, sv.x), inv2);  // dims (4q, 4q+1)
    uint32_t r23 = hmul2u(hadd2u(a23, sv.y), inv2);  // dims (4q+2, 4q+3)
    // row-major coalesced store: 64 lanes cover the row's 256 B
    agg32[(size_t)n*64 + (q << 1) + half] = half ? r23 : r01;
  }
}

// ---- LDS-free 16-row-per-wave GEMM (f16 MFMA) fused with row L2-normalize;
//      A-frags read directly from row-major agg ----
__global__ __launch_bounds__(256) void k_gemm(const uint16_t* __restrict__ agg,
                                              const uint16_t* __restrict__ wsw,
                                              float* __restrict__ out){
  int tid = threadIdx.x, wid = tid >> 6, lane = tid & 63;
  int g = blockIdx.x*4 + wid;                        // 16-row group
  if (g >= 6250) return;                             // wave-uniform pad exit (6250*16 == NN)
  const char* aggb = (const char*)agg;
  const f16x8* Bf = (const f16x8*)wsw;
  int row = g*16 + (lane & 15), gk = lane >> 4;
  f16x8 a[4];
  #pragma unroll
  for (int kt=0; kt<4; kt++)
    a[kt] = *(const f16x8*)(aggb + (size_t)row*256 + kt*64 + gk*16);

  f32x4 acc[8];
  #pragma unroll
  for (int ct=0;ct<8;ct++) acc[ct] = (f32x4){0.f,0.f,0.f,0.f};
  #pragma unroll
  for (int ct=0;ct<8;ct++){
    #pragma unroll
    for (int kt=0;kt<4;kt++)
      acc[ct] = __builtin_amdgcn_mfma_f32_16x16x32_f16(a[kt], Bf[(ct*4+kt)*64 + lane], acc[ct], 0, 0, 0);
  }
  float sq[4] = {0.f,0.f,0.f,0.f};
  #pragma unroll
  for (int ct=0;ct<8;ct++){
    #pragma unroll
    for (int i=0;i<4;i++) sq[i] += acc[ct][i]*acc[ct][i];
  }
  #pragma unroll
  for (int m=1;m<16;m<<=1){
    #pragma unroll
    for (int i=0;i<4;i++) sq[i] += __shfl_xor(sq[i], m);
  }
  float sc4[4];
  #pragma unroll
  for (int i=0;i<4;i++) sc4[i] = 1.0f / fmaxf(sqrtf(sq[i]), 1e-12f);

  int col = lane & 15;
  int rb = g*16 + (gk << 2);
  #pragma unroll
  for (int i=0;i<4;i++){
    int n = rb + i;                                  // always < NN (no partial tiles)
    #pragma unroll
    for (int ct=0;ct<8;ct++)
      out[(size_t)n*DD + (ct<<4) + col] = acc[ct][i]*sc4[i];
  }
}

extern "C" void kernel_launch(void* const* d_in, const int* in_sizes, int n_in,
                              void* d_out, int out_size, void* d_ws, size_t ws_size,
                              hipStream_t stream){
  const float* x = (const float*)d_in[0];
  const int*  ei = (const int*)d_in[1];
  const float* w = (const float*)d_in[2];
  float* out = (float*)d_out;
  char* ws = (char*)d_ws;
  (void)in_sizes; (void)n_in; (void)out_size; (void)ws_size;

  size_t off = 0;
  uint16_t* x16 = (uint16_t*)(ws + off); off += (size_t)NN*DD*2;         // 25,600,000
  uint16_t* agg = (uint16_t*)(ws + off); off += (size_t)NN*DD*2;         // 25,600,000
  uint16_t* wsw = (uint16_t*)(ws + off); off += (size_t)DD*DD*2;         // 32,768
  uint32_t* ibuf = (uint32_t*)(ws + off); off += (size_t)NBKT*CAPB*4;    // 7,006,720
  int* bktres   = (int*)(ws + off); off += (size_t)NBKT*16*4;            // 25,024
  uint32_t* rowinfo = (uint32_t*)(ws + off); off += (size_t)NBKT*256*4;  // 400,384 (~58.7 MB)

  hipMemsetAsync(bktres, 0, (size_t)NBKT*16*4, stream);
  k_front<<<6673, 512, 0, stream>>>(ei, bktres, ibuf, (const float4*)x, (uint2*)x16, w, wsw);
  k_part2<<<NBKT, 512, 0, stream>>>(bktres, ibuf, rowinfo);
  k_gather<<<NBIN, 256, 0, stream>>>((const uint2*)x16, ibuf, rowinfo, (uint32_t*)agg);
  k_gemm<<<1563, 256, 0, stream>>>(agg, wsw, out);
}

// Round 16
// 127.559 us; speedup vs baseline: 1.1443x; 1.0029x over previous
//
#include <hip/hip_runtime.h>
#include <hip/hip_fp16.h>
#include <stdint.h>

#define NN 100000
#define NE 1600000
#define DD 128

#define NBKT 391            // buckets of 256 rows: 391*256 = 100096 >= NN
#define CAPB 4480           // per-bucket record capacity (mean 4096, sd ~64, +6sd)
#define NBIN 3125           // 32-row bins: 3125*32 == NN exactly
#define GCAP 1024           // per-bin staged col capacity (mean 512, max ~650)

typedef _Float16 f16x8 __attribute__((ext_vector_type(8)));
typedef float f32x4 __attribute__((ext_vector_type(4)));

__device__ __forceinline__ uint32_t hadd2u(uint32_t a, uint32_t b){
  union { uint32_t u; __half2 h; } x, y;
  x.u = a; y.u = b;
  x.h = __hadd2(x.h, y.h);
  return x.u;
}
__device__ __forceinline__ uint32_t hmul2u(uint32_t a, __half2 m){
  union { uint32_t u; __half2 h; } x; x.u = a;
  x.h = __hmul2(x.h, m);
  return x.u;
}

// ---- pass 1 (1024-thr): blocks 0-390 partition edges into fat buckets (4-iter
//      chains, no BW competition); blocks 391-406 convert W -> frag-linear f16 ----
__global__ __launch_bounds__(1024) void k_part1(
    const int* __restrict__ ei, int* __restrict__ bktres, uint32_t* __restrict__ ibuf,
    const float* __restrict__ w, uint16_t* __restrict__ wsw){
  int b = blockIdx.x, t = threadIdx.x;
  if (b < NBKT){                                     // ---- part1 ----
    __shared__ int sh[NBKT];
    int e0 = b*4096;
    for (int i=t; i<NBKT; i+=1024) sh[i] = 0;
    __syncthreads();
    int rr[4], cc[4];
    #pragma unroll
    for (int j=0;j<4;j++){
      int e = e0 + j*1024 + t;
      rr[j] = -1;
      if (e < NE){
        rr[j] = ei[e]; cc[j] = ei[NE + e];           // no self loops by construction
        atomicAdd(&sh[rr[j] >> 8], 1);
      }
    }
    __syncthreads();
    for (int i=t; i<NBKT; i+=1024){
      int v = sh[i];
      sh[i] = v ? atomicAdd(&bktres[i*16], v) : 0;   // reserve contiguous chunk
    }
    __syncthreads();
    #pragma unroll
    for (int j=0;j<4;j++){
      if (rr[j] >= 0){
        int bk = rr[j] >> 8;
        int p = atomicAdd(&sh[bk], 1);
        if (p < CAPB)
          ibuf[(size_t)bk*CAPB + p] = (uint32_t)(((rr[j] & 255) << 17) | cc[j]);
      }
    }
  } else {                                           // ---- W -> frag-linear f16 ----
    int wi = (b - NBKT)*1024 + t;                    // 16 blocks = 16384 exact
    int j = wi & 7, l = (wi >> 3) & 63, kt = (wi >> 9) & 3, ct = wi >> 11;
    int k = kt*32 + ((l >> 4) & 3)*8 + j;
    int d = ct*16 + (l & 15);
    union { _Float16 h; uint16_t u; } cv; cv.h = (_Float16)w[k*DD + d];
    wsw[wi] = cv.u;
  }
}

// ---- mid (1024-thr): blocks 0-390 sort buckets in LDS (4.4-iter chains);
//      blocks 391-3515 stream x -> f16 (BW-bound backfill keeps CUs fed) ----
__global__ __launch_bounds__(1024) void k_mid(
    const int* __restrict__ bktres, uint32_t* __restrict__ ibuf,
    uint32_t* __restrict__ rowinfo,
    const float4* __restrict__ x, uint2* __restrict__ x16){
  int t = threadIdx.x, b = blockIdx.x;
  if (b >= NBKT){                                    // ---- x -> f16 ----
    int i = (b - NBKT)*1024 + t;                     // 3125 blocks = 3.2M float4 exact
    float4 v = x[i];
    union { _Float16 h[4]; uint2 u; } r;
    r.h[0] = (_Float16)v.x; r.h[1] = (_Float16)v.y;
    r.h[2] = (_Float16)v.z; r.h[3] = (_Float16)v.w;
    x16[i] = r.u;
    return;
  }
  // ---- part2: bucket sort ----
  __shared__ uint32_t s_rec[CAPB];                   // 17.9 KB
  __shared__ int s_deg[256], s_off[256], s_cur[256];
  int lane = t & 63, wid = t >> 6;
  int cnt = bktres[b*16]; if (cnt > CAPB) cnt = CAPB;
  size_t bb = (size_t)b*CAPB;
  if (t < 256) s_deg[t] = 0;
  __syncthreads();
  for (int i=t; i<cnt; i+=1024){
    uint32_t rec = ibuf[bb + i];
    s_rec[i] = rec;
    atomicAdd(&s_deg[rec >> 17], 1);
  }
  __syncthreads();
  if (wid == 0){                                     // wave-0 scan of 256 degs
    int carry = 0;
    for (int ch=0; ch<4; ch++){
      int idx = ch*64 + lane;
      int o = s_deg[idx], v = o;
      #pragma unroll
      for (int d=1; d<64; d<<=1){ int y = __shfl_up(v, d); if (lane >= d) v += y; }
      int ex = carry + v - o;
      s_off[idx] = ex; s_cur[idx] = ex;
      carry += __shfl(v, 63);
    }
  }
  __syncthreads();
  if (t < 256){
    int dgc = s_deg[t] > 255 ? 255 : s_deg[t];
    rowinfo[b*256 + t] = ((uint32_t)s_off[t] << 8) | (uint32_t)dgc;
  }
  for (int i=t; i<cnt; i+=1024){
    uint32_t rec = s_rec[i];
    int p = atomicAdd(&s_cur[rec >> 17], 1);
    ibuf[bb + p] = rec & 0x1FFFFu;                   // col only, row-sorted, L2-hot
  }
}

// ---- gather: 32-row bin per 256-thr block, 4 waves x 8 rows; dual-edge f16 mean;
//      row-major coalesced agg store (256 B/row). At its ~3.5 TB/s fill ceiling. ----
__global__ __launch_bounds__(256) void k_gather(
    const uint2* __restrict__ xp, const uint32_t* __restrict__ ibuf,
    const uint32_t* __restrict__ rowinfo, uint32_t* __restrict__ agg32){
  __shared__ int s_col[GCAP];                        // 4 KB
  __shared__ int s_loc[32], s_deg[32];
  int t = threadIdx.x, wid = t >> 6, lane = t & 63;
  int b = blockIdx.x;
  int row0 = b << 5;                                 // 32 rows, all inside bucket row0>>8
  if (t < 32){
    uint32_t info = rowinfo[row0 + t];
    s_loc[t] = (int)(info >> 8);
    s_deg[t] = (int)(info & 255u);
  }
  __syncthreads();
  int base = s_loc[0];
  int len = s_loc[31] + s_deg[31] - base; if (len > GCAP) len = GCAP;
  size_t bb = (size_t)(row0 >> 8)*CAPB + base;
  for (int i=t; i<len; i+=256) s_col[i] = (int)ibuf[bb + i];
  __syncthreads();

  int q = lane & 31, half = lane >> 5;               // lanes 0-31 even edges, 32-63 odd
  for (int lr = wid; lr < 32; lr += 4){
    int n = row0 + lr;
    int dg  = s_deg[lr];
    int off = s_loc[lr] - base;
    uint2 sv = xp[(size_t)n*32 + q];                 // self f16x4: dims 4q..4q+3
    uint32_t a01 = 0u, a23 = 0u;                     // packed f16x2 accumulators
    int j = 0;
    for (; j+16 <= dg; j += 16){                     // 8 dual loads in flight
      int c0 = s_col[off+j+half],    c1 = s_col[off+j+2+half];
      int c2 = s_col[off+j+4+half],  c3 = s_col[off+j+6+half];
      int c4 = s_col[off+j+8+half],  c5 = s_col[off+j+10+half];
      int c6 = s_col[off+j+12+half], c7 = s_col[off+j+14+half];
      uint2 v0 = xp[(size_t)c0*32 + q]; uint2 v1 = xp[(size_t)c1*32 + q];
      uint2 v2 = xp[(size_t)c2*32 + q]; uint2 v3 = xp[(size_t)c3*32 + q];
      uint2 v4 = xp[(size_t)c4*32 + q]; uint2 v5 = xp[(size_t)c5*32 + q];
      uint2 v6 = xp[(size_t)c6*32 + q]; uint2 v7 = xp[(size_t)c7*32 + q];
      a01 = hadd2u(a01, v0.x); a23 = hadd2u(a23, v0.y);
      a01 = hadd2u(a01, v1.x); a23 = hadd2u(a23, v1.y);
      a01 = hadd2u(a01, v2.x); a23 = hadd2u(a23, v2.y);
      a01 = hadd2u(a01, v3.x); a23 = hadd2u(a23, v3.y);
      a01 = hadd2u(a01, v4.x); a23 = hadd2u(a23, v4.y);
      a01 = hadd2u(a01, v5.x); a23 = hadd2u(a23, v5.y);
      a01 = hadd2u(a01, v6.x); a23 = hadd2u(a23, v6.y);
      a01 = hadd2u(a01, v7.x); a23 = hadd2u(a23, v7.y);
    }
    for (; j+8 <= dg; j += 8){
      int c0 = s_col[off+j+half],   c1 = s_col[off+j+2+half];
      int c2 = s_col[off+j+4+half], c3 = s_col[off+j+6+half];
      uint2 v0 = xp[(size_t)c0*32 + q]; uint2 v1 = xp[(size_t)c1*32 + q];
      uint2 v2 = xp[(size_t)c2*32 + q]; uint2 v3 = xp[(size_t)c3*32 + q];
      a01 = hadd2u(a01, v0.x); a23 = hadd2u(a23, v0.y);
      a01 = hadd2u(a01, v1.x); a23 = hadd2u(a23, v1.y);
      a01 = hadd2u(a01, v2.x); a23 = hadd2u(a23, v2.y);
      a01 = hadd2u(a01, v3.x); a23 = hadd2u(a23, v3.y);
    }
    for (; j+2 <= dg; j += 2){
      int c0 = s_col[off+j+half];
      uint2 v0 = xp[(size_t)c0*32 + q];
      a01 = hadd2u(a01, v0.x); a23 = hadd2u(a23, v0.y);
    }
    if (j < dg){                                     // odd tail: half 0 only
      int c0 = s_col[off+j];
      uint2 v0 = xp[(size_t)c0*32 + q];
      a01 = hadd2u(a01, half ? 0u : v0.x);
      a23 = hadd2u(a23, half ? 0u : v0.y);
    }
    a01 = hadd2u(a01, (uint32_t)__shfl_xor((int)a01, 32));
    a23 = hadd2u(a23, (uint32_t)__shfl_xor((int)a23, 32));
    __half2 inv2 = __float2half2_rn(1.0f / (float)(dg + 1));
    uint32_t r01 = hmul2u(hadd2u(a01, sv.x), inv2);  // dims (4q, 4q+1)
    uint32_t r23 = hmul2u(hadd2u(a23, sv.y), inv2);  // dims (4q+2, 4q+3)
    // row-major coalesced store: 64 lanes cover the row's 256 B
    agg32[(size_t)n*64 + (q << 1) + half] = half ? r23 : r01;
  }
}

// ---- LDS-free 16-row-per-wave GEMM (f16 MFMA) fused with row L2-normalize;
//      A-frags read directly from row-major agg ----
__global__ __launch_bounds__(256) void k_gemm(const uint16_t* __restrict__ agg,
                                              const uint16_t* __restrict__ wsw,
                                              float* __restrict__ out){
  int tid = threadIdx.x, wid = tid >> 6, lane = tid & 63;
  int g = blockIdx.x*4 + wid;                        // 16-row group
  if (g >= 6250) return;                             // wave-uniform pad exit (6250*16 == NN)
  const char* aggb = (const char*)agg;
  const f16x8* Bf = (const f16x8*)wsw;
  int row = g*16 + (lane & 15), gk = lane >> 4;
  f16x8 a[4];
  #pragma unroll
  for (int kt=0; kt<4; kt++)
    a[kt] = *(const f16x8*)(aggb + (size_t)row*256 + kt*64 + gk*16);

  f32x4 acc[8];
  #pragma unroll
  for (int ct=0;ct<8;ct++) acc[ct] = (f32x4){0.f,0.f,0.f,0.f};
  #pragma unroll
  for (int ct=0;ct<8;ct++){
    #pragma unroll
    for (int kt=0;kt<4;kt++)
      acc[ct] = __builtin_amdgcn_mfma_f32_16x16x32_f16(a[kt], Bf[(ct*4+kt)*64 + lane], acc[ct], 0, 0, 0);
  }
  float sq[4] = {0.f,0.f,0.f,0.f};
  #pragma unroll
  for (int ct=0;ct<8;ct++){
    #pragma unroll
    for (int i=0;i<4;i++) sq[i] += acc[ct][i]*acc[ct][i];
  }
  #pragma unroll
  for (int m=1;m<16;m<<=1){
    #pragma unroll
    for (int i=0;i<4;i++) sq[i] += __shfl_xor(sq[i], m);
  }
  float sc4[4];
  #pragma unroll
  for (int i=0;i<4;i++) sc4[i] = 1.0f / fmaxf(sqrtf(sq[i]), 1e-12f);

  int col = lane & 15;
  int rb = g*16 + (gk << 2);
  #pragma unroll
  for (int i=0;i<4;i++){
    int n = rb + i;                                  // always < NN (no partial tiles)
    #pragma unroll
    for (int ct=0;ct<8;ct++)
      out[(size_t)n*DD + (ct<<4) + col] = acc[ct][i]*sc4[i];
  }
}

extern "C" void kernel_launch(void* const* d_in, const int* in_sizes, int n_in,
                              void* d_out, int out_size, void* d_ws, size_t ws_size,
                              hipStream_t stream){
  const float* x = (const float*)d_in[0];
  const int*  ei = (const int*)d_in[1];
  const float* w = (const float*)d_in[2];
  float* out = (float*)d_out;
  char* ws = (char*)d_ws;
  (void)in_sizes; (void)n_in; (void)out_size; (void)ws_size;

  size_t off = 0;
  uint16_t* x16 = (uint16_t*)(ws + off); off += (size_t)NN*DD*2;         // 25,600,000
  uint16_t* agg = (uint16_t*)(ws + off); off += (size_t)NN*DD*2;         // 25,600,000
  uint16_t* wsw = (uint16_t*)(ws + off); off += (size_t)DD*DD*2;         // 32,768
  uint32_t* ibuf = (uint32_t*)(ws + off); off += (size_t)NBKT*CAPB*4;    // 7,006,720
  int* bktres   = (int*)(ws + off); off += (size_t)NBKT*16*4;            // 25,024
  uint32_t* rowinfo = (uint32_t*)(ws + off); off += (size_t)NBKT*256*4;  // 400,384 (~58.7 MB)

  hipMemsetAsync(bktres, 0, (size_t)NBKT*16*4, stream);
  k_part1<<<NBKT + 16, 1024, 0, stream>>>(ei, bktres, ibuf, w, wsw);
  k_mid<<<NBKT + 3125, 1024, 0, stream>>>(bktres, ibuf, rowinfo, (const float4*)x, (uint2*)x16);
  k_gather<<<NBIN, 256, 0, stream>>>((const uint2*)x16, ibuf, rowinfo, (uint32_t*)agg);
  k_gemm<<<1563, 256, 0, stream>>>(agg, wsw, out);
}